// Round 1
// baseline (435.436 us; speedup 1.0000x reference)
//
#include <hip/hip_runtime.h>
#include <hip/hip_bf16.h>
#include <stdint.h>

// TermEncoder GAT: N=50000, E=800000, D=128, H=2, C=128, HC=256
// R9: full fp16 pipeline. r8 lesson: compiler defeats register dbuf (VGPR
// 96->68, no gain). Instead cut the work: single fp16 MFMA (no hi/lo split)
// -> 8 loads + 16 MFMAs per k-step (was 16+48). fp16 storage for x/W/h/xl/p;
// f32 accumulate + f32 alpha/bias/output. Error budget: ~2^-10/product,
// ~3-5e-4/GEMM, well under 8.7e-3 threshold (at 1.95e-3 now).
// R10: identical resubmit — round 0 bench failed on container acquisition
// (infra), no counters. Re-establish 441.6 us baseline + capture profile.
#define HC 256
#define NEG_SLOPE 0.2f
#define SOFTMAX_EPS 1e-16f

typedef float floatx4 __attribute__((ext_vector_type(4)));
typedef _Float16 half8v __attribute__((ext_vector_type(8)));

// ---------------------------------------------------------------------------
// dtype sniffing: flags[0]=float-is-bf16, flags[1]=edge-index-is-int64.
// ---------------------------------------------------------------------------
__global__ void detect_kernel(const uint32_t* __restrict__ xw,
                              const uint32_t* __restrict__ ew,
                              int* __restrict__ flags) {
    __shared__ int cnt_bf16, cnt_odd_nz;
    const int t = threadIdx.x;
    if (t == 0) { cnt_bf16 = 0; cnt_odd_nz = 0; }
    __syncthreads();
    uint32_t w = xw[t];
    uint32_t ef = ((w & 0xFFFFu) >> 7) & 0xFFu;
    if (ef >= 90u && ef <= 135u) atomicAdd(&cnt_bf16, 1);
    if (t < 64 && ew[2 * t + 1] != 0u) atomicAdd(&cnt_odd_nz, 1);
    __syncthreads();
    if (t == 0) {
        flags[0] = (cnt_bf16 > 192) ? 1 : 0;
        flags[1] = (cnt_odd_nz == 0) ? 1 : 0;
    }
}

__device__ __forceinline__ float in_load(const void* p, int i, int is_bf16) {
    return is_bf16 ? (float)((const __bf16*)p)[i] : ((const float*)p)[i];
}

// six small f32 tensors (att_l1, att_r1, att_l2, att_r2, bp1, bp2)
__global__ void conv_small_kernel(const void* a0, float* o0, int n0,
                                  const void* a1, float* o1, int n1,
                                  const void* a2, float* o2, int n2,
                                  const void* a3, float* o3, int n3,
                                  const void* a4, float* o4, int n4,
                                  const void* a5, float* o5, int n5,
                                  const int* __restrict__ flags) {
    const int t = threadIdx.x;
    const int fb = flags[0];
    if (t < n0) o0[t] = in_load(a0, t, fb);
    if (t < n1) o1[t] = in_load(a1, t, fb);
    if (t < n2) o2[t] = in_load(a2, t, fb);
    if (t < n3) o3[t] = in_load(a3, t, fb);
    if (t < n4) o4[t] = in_load(a4, t, fb);
    if (t < n5) o5[t] = in_load(a5, t, fb);
}

// convert one tensor to fp16
__global__ void convh_kernel(const void* __restrict__ in, _Float16* __restrict__ out,
                             int n, const int* __restrict__ flags) {
    int i = blockIdx.x * blockDim.x + threadIdx.x;
    if (i < n) out[i] = (_Float16)in_load(in, i, flags[0]);
}

// convert the 4 weight matrices to fp16 in one launch
__global__ void conv4_kernel(const void* i0, _Float16* o0, int n0,
                             const void* i1, _Float16* o1, int n1,
                             const void* i2, _Float16* o2, int n2,
                             const void* i3, _Float16* o3, int n3,
                             const int* __restrict__ flags) {
    int idx = blockIdx.x * blockDim.x + threadIdx.x;
    const void* in;
    _Float16* po;
    int off = idx;
    if (off < n0)      { in = i0; po = o0; }
    else if ((off -= n0) < n1) { in = i1; po = o1; }
    else if ((off -= n1) < n2) { in = i2; po = o2; }
    else if ((off -= n2) < n3) { in = i3; po = o3; }
    else return;
    po[off] = (_Float16)in_load(in, off, flags[0]);
}

// ---------------------------------------------------------------------------
// GEMM: C[M,O] = A[M,KTEMP]@B[O,KTEMP]^T (+bias), fp16 operands, f32 acc.
// Block = 256 thr = 4 waves, M-tile 64; wave w owns O/4 cols (TW tiles).
// Per k-step: 4 A + TW B fragment loads, then 4*TW MFMAs. K fully unrolled.
// ALPHA (OTILES==16): fused per-row per-head att dots (f32).
// OMODE: 0=f32 out, 2=fp16 out.
// ---------------------------------------------------------------------------
template <int KTEMP, int OTILES, bool BIAS, bool ALPHA, int OMODE>
__global__ __launch_bounds__(256, 2) void gemm_bt(
    const _Float16* __restrict__ A, const _Float16* __restrict__ B,
    const float* __restrict__ bias,
    float* __restrict__ C, _Float16* __restrict__ Cf16,
    const float* __restrict__ attl, const float* __restrict__ attr,
    float* __restrict__ al, float* __restrict__ ar,
    int M) {
    static_assert(!ALPHA || OTILES == 16, "alpha fusion assumes O=256");
    constexpr int TW = OTILES / 4;
    constexpr int O = OTILES * 16;
    const int tid = threadIdx.x;
    const int lane = tid & 63;
    const int wave = tid >> 6;
    const int mbase = blockIdx.x * 64;
    const int l15 = lane & 15;
    const int q = lane >> 4;
    const int kq = q * 8;
    const int wc = wave * TW * 16;

    int arow[4];
#pragma unroll
    for (int rt = 0; rt < 4; rt++) arow[rt] = min(mbase + rt * 16 + l15, M - 1);

    floatx4 acc[4][TW];
#pragma unroll
    for (int rt = 0; rt < 4; rt++)
#pragma unroll
        for (int tt = 0; tt < TW; tt++) acc[rt][tt] = (floatx4){0.f, 0.f, 0.f, 0.f};

    constexpr int KSTEPS = KTEMP / 32;
#pragma unroll
    for (int ks = 0; ks < KSTEPS; ks++) {
        const int k0 = ks * 32;
        half8v af[4], bf[TW];
#pragma unroll
        for (int rt = 0; rt < 4; rt++)
            af[rt] = *(const half8v*)(A + (size_t)arow[rt] * KTEMP + k0 + kq);
#pragma unroll
        for (int tt = 0; tt < TW; tt++)
            bf[tt] = *(const half8v*)(B + (size_t)(wc + tt * 16 + l15) * KTEMP + k0 + kq);
#pragma unroll
        for (int rt = 0; rt < 4; rt++)
#pragma unroll
            for (int tt = 0; tt < TW; tt++)
                acc[rt][tt] = __builtin_amdgcn_mfma_f32_16x16x32_f16(af[rt], bf[tt], acc[rt][tt], 0, 0, 0);
    }

    // C/D layout: col = lane&15, row(in tile) = q*4 + reg  [m89/m91; dtype-indep]
    float aLp[4][4], aRp[4][4];
    if constexpr (ALPHA) {
#pragma unroll
        for (int rt = 0; rt < 4; rt++)
#pragma unroll
            for (int r = 0; r < 4; r++) { aLp[rt][r] = 0.f; aRp[rt][r] = 0.f; }
    }

#pragma unroll
    for (int rt = 0; rt < 4; rt++) {
        const int rb = mbase + rt * 16 + q * 4;
#pragma unroll
        for (int tt = 0; tt < TW; tt++) {
            const int gcol = wc + tt * 16 + l15;
            float atlv = 0.f, atrv = 0.f;
            if constexpr (ALPHA) { atlv = attl[gcol]; atrv = attr[gcol]; }
#pragma unroll
            for (int r = 0; r < 4; r++) {
                float v = acc[rt][tt][r];
                if constexpr (BIAS) v += bias[gcol];
                if constexpr (ALPHA) { aLp[rt][r] += v * atlv; aRp[rt][r] += v * atrv; }
                const int grow = rb + r;
                if (grow < M) {
                    if constexpr (OMODE == 2) {
                        Cf16[(size_t)grow * O + gcol] = (_Float16)v;
                    } else {
                        C[(size_t)grow * O + gcol] = v;
                    }
                }
            }
        }
    }

    if constexpr (ALPHA) {
        __shared__ float sAL[4][64], sAR[4][64];
#pragma unroll
        for (int rt = 0; rt < 4; rt++)
#pragma unroll
            for (int r = 0; r < 4; r++) {
                float vl = aLp[rt][r], vr = aRp[rt][r];
                vl += __shfl_xor(vl, 1); vl += __shfl_xor(vl, 2);
                vl += __shfl_xor(vl, 4); vl += __shfl_xor(vl, 8);
                vr += __shfl_xor(vr, 1); vr += __shfl_xor(vr, 2);
                vr += __shfl_xor(vr, 4); vr += __shfl_xor(vr, 8);
                if (l15 == 0) {
                    sAL[wave][rt * 16 + q * 4 + r] = vl;
                    sAR[wave][rt * 16 + q * 4 + r] = vr;
                }
            }
        __syncthreads();
        if (tid < 64) {
            const int grow = mbase + tid;
            if (grow < M) {
                al[2 * grow]     = sAL[0][tid] + sAL[1][tid];   // head 0 = waves 0,1
                al[2 * grow + 1] = sAL[2][tid] + sAL[3][tid];   // head 1 = waves 2,3
                ar[2 * grow]     = sAR[0][tid] + sAR[1][tid];
                ar[2 * grow + 1] = sAR[2][tid] + sAR[3][tid];
            }
        }
    }
}

// ---------------------------------------------------------------------------
// CSR build
// ---------------------------------------------------------------------------
__device__ __forceinline__ int edge_src(const int* ei, int E, int e, int is64) {
    return is64 ? ei[2 * (size_t)e] : ei[e];
}
__device__ __forceinline__ int edge_dst(const int* ei, int E, int e, int is64) {
    return is64 ? ei[2 * (size_t)E + 2 * (size_t)e] : ei[(size_t)E + e];
}

__global__ void count_kernel(const int* __restrict__ ei, int E,
                             const int* __restrict__ flags, int* __restrict__ counts) {
    int e = blockIdx.x * blockDim.x + threadIdx.x;
    if (e < E) atomicAdd(&counts[edge_dst(ei, E, e, flags[1])], 1);
}

__global__ __launch_bounds__(1024) void scan1_kernel(const int* __restrict__ counts,
                                                     int* __restrict__ incl,
                                                     int* __restrict__ bsum, int N) {
    __shared__ int tmp[1024];
    const int t = threadIdx.x;
    const int i = blockIdx.x * 1024 + t;
    int v = (i < N) ? counts[i] : 0;
    tmp[t] = v;
    __syncthreads();
    for (int off = 1; off < 1024; off <<= 1) {
        int x = (t >= off) ? tmp[t - off] : 0;
        __syncthreads();
        tmp[t] += x;
        __syncthreads();
    }
    if (i < N) incl[i] = tmp[t];
    if (t == 1023) bsum[blockIdx.x] = tmp[1023];
}

__global__ void scan2_kernel(const int* __restrict__ bsum, int* __restrict__ boffs,
                             int nb, int* __restrict__ row_ptr, int N) {
    if (threadIdx.x == 0) {
        int run = 0;
        for (int b = 0; b < nb; b++) { boffs[b] = run; run += bsum[b]; }
        row_ptr[N] = run;
    }
}

__global__ void scan3_kernel(const int* __restrict__ incl, const int* __restrict__ counts,
                             const int* __restrict__ boffs, int* __restrict__ row_ptr,
                             int* __restrict__ fill, int N) {
    int i = blockIdx.x * blockDim.x + threadIdx.x;
    if (i < N) {
        int v = boffs[i >> 10] + incl[i] - counts[i];
        row_ptr[i] = v;
        fill[i] = v;
    }
}

__global__ void scatter_kernel(const int* __restrict__ ei, int E,
                               const int* __restrict__ flags,
                               int* __restrict__ fill, int* __restrict__ esrc) {
    int e = blockIdx.x * blockDim.x + threadIdx.x;
    if (e < E) {
        int is64 = flags[1];
        int s = edge_src(ei, E, e, is64);
        int d = edge_dst(ei, E, e, is64);
        int pos = atomicAdd(&fill[d], 1);
        esrc[pos] = s;
    }
}

// ---------------------------------------------------------------------------
// Fused segment softmax + aggregation, wave-per-node, online softmax.
// Gather: half-wave per edge (16 B/lane), output fp16 h (single tensor).
// ---------------------------------------------------------------------------
__global__ __launch_bounds__(256) void agg_fused_kernel(
    const _Float16* __restrict__ xl,
    const float* __restrict__ al, const float* __restrict__ ar,
    const int* __restrict__ row_ptr, const int* __restrict__ esrc,
    _Float16* __restrict__ hout, int N) {
    const int wid = (blockIdx.x * 256 + threadIdx.x) >> 6;   // node id
    if (wid >= N) return;
    const int lane = threadIdx.x & 63;
    const int half = lane >> 5;          // which edge of the pair
    const int c8 = (lane & 31) * 8;      // my 8-column base
    const int hsel = c8 >> 7;            // head of my columns
    const int s0 = row_ptr[wid], e0 = row_ptr[wid + 1];
    const float ar0 = ar[2 * wid], ar1 = ar[2 * wid + 1];

    float acc[8];
#pragma unroll
    for (int c = 0; c < 8; c++) acc[c] = 0.f;
    float m0 = -INFINITY, m1 = -INFINITY, l0 = 0.f, l1 = 0.f;

    for (int base = s0; base < e0; base += 64) {
        const int n = min(64, e0 - base);
        int s = 0;
        float lg0 = -INFINITY, lg1 = -INFINITY;
        if (lane < n) {
            s = esrc[base + lane];
            float2 av = *(const float2*)(al + 2 * s);
            lg0 = av.x + ar0; lg0 = lg0 > 0.f ? lg0 : NEG_SLOPE * lg0;
            lg1 = av.y + ar1; lg1 = lg1 > 0.f ? lg1 : NEG_SLOPE * lg1;
        }
        float cm0 = lg0, cm1 = lg1;
#pragma unroll
        for (int off = 1; off < 64; off <<= 1) {
            cm0 = fmaxf(cm0, __shfl_xor(cm0, off));
            cm1 = fmaxf(cm1, __shfl_xor(cm1, off));
        }
        const float nm0 = fmaxf(m0, cm0), nm1 = fmaxf(m1, cm1);
        const float sc0 = __expf(m0 - nm0), sc1 = __expf(m1 - nm1);
        m0 = nm0; m1 = nm1;
        float p0 = 0.f, p1 = 0.f;
        if (lane < n) { p0 = __expf(lg0 - nm0); p1 = __expf(lg1 - nm1); }
        l0 = l0 * sc0 + p0;
        l1 = l1 * sc1 + p1;
        const float asc = hsel ? sc1 : sc0;
#pragma unroll
        for (int c = 0; c < 8; c++) acc[c] *= asc;

#pragma unroll 4
        for (int j = 0; j < n; j += 2) {
            const int jj = j + half;
            const float w0 = __shfl(p0, jj);
            const float w1 = __shfl(p1, jj);
            const int ss = __shfl(s, jj);
            if (jj < n) {
                const float wv = hsel ? w1 : w0;
                half8v xv = *(const half8v*)(xl + (size_t)ss * HC + c8);
#pragma unroll
                for (int c = 0; c < 8; c++) acc[c] += wv * (float)xv[c];
            }
        }
    }

#pragma unroll
    for (int off = 1; off < 64; off <<= 1) {
        l0 += __shfl_xor(l0, off);
        l1 += __shfl_xor(l1, off);
    }
    const float winv = 1.f / ((hsel ? l1 : l0) + SOFTMAX_EPS);

#pragma unroll
    for (int c = 0; c < 8; c++) {
        acc[c] += __shfl_xor(acc[c], 32);
        acc[c] = fmaxf(acc[c] * winv, 0.f);   // fused relu
    }
    if (half == 0) {
        half8v vo;
#pragma unroll
        for (int c = 0; c < 8; c++) vo[c] = (_Float16)acc[c];
        *(half8v*)(hout + (size_t)wid * HC + c8) = vo;
    }
}

// ---------------------------------------------------------------------------
extern "C" void kernel_launch(void* const* d_in, const int* in_sizes, int n_in,
                              void* d_out, int out_size, void* d_ws, size_t ws_size,
                              hipStream_t stream) {
    const int D = 128;
    const int N = in_sizes[0] / D;   // 50000
    const int E = in_sizes[1] / 2;   // 800000
    const int* ei = (const int*)d_in[1];

    char* w = (char*)d_ws;
    auto alloc = [&](size_t bytes) {
        void* p = w;
        w += (bytes + 255) & ~(size_t)255;
        return p;
    };
    int*      flags  = (int*)     alloc(256);
    _Float16* x16    = (_Float16*)alloc((size_t)N * D * 2);      // x; reused as p
    _Float16* W1f    = (_Float16*)alloc((size_t)in_sizes[2] * 2);
    _Float16* W2f    = (_Float16*)alloc((size_t)in_sizes[5] * 2);
    _Float16* Wp1f   = (_Float16*)alloc((size_t)in_sizes[8] * 2);
    _Float16* Wp2f   = (_Float16*)alloc((size_t)in_sizes[10] * 2);
    float*    atl1   = (float*)   alloc((size_t)in_sizes[3] * 4);
    float*    atr1   = (float*)   alloc((size_t)in_sizes[4] * 4);
    float*    atl2   = (float*)   alloc((size_t)in_sizes[6] * 4);
    float*    atr2   = (float*)   alloc((size_t)in_sizes[7] * 4);
    float*    bfp1   = (float*)   alloc((size_t)in_sizes[9] * 4);
    float*    bfp2   = (float*)   alloc((size_t)in_sizes[11] * 4);
    _Float16* xl16   = (_Float16*)alloc((size_t)N * HC * 2);     // 25.6 MB
    _Float16* h16    = (_Float16*)alloc((size_t)N * HC * 2);     // 25.6 MB
    float*    al     = (float*)   alloc((size_t)N * 2 * 4);
    float*    ar     = (float*)   alloc((size_t)N * 2 * 4);
    int*      counts = (int*)     alloc((size_t)N * 4);
    int*      incl   = (int*)     alloc((size_t)N * 4);
    int*      row_ptr= (int*)     alloc((size_t)(N + 1) * 4);
    int*      fill   = (int*)     alloc((size_t)N * 4);
    int*      bsum   = (int*)     alloc(1024);
    int*      boffs  = (int*)     alloc(1024);
    int*      esrc   = (int*)     alloc((size_t)E * 4);

    const int EB = (E + 255) / 256;
    const int GM = (N + 63) / 64;
    const int NB1024 = (N + 1023) / 1024;
    const int AGG_B = (N + 3) / 4;   // wave per node, 4 waves/block

    // 0. dtype sniff + canonicalize (fp16 operands, f32 att/bias)
    detect_kernel<<<1, 256, 0, stream>>>((const uint32_t*)d_in[0], (const uint32_t*)d_in[1], flags);
    conv_small_kernel<<<1, 256, 0, stream>>>(d_in[3], atl1, in_sizes[3],
                                             d_in[4], atr1, in_sizes[4],
                                             d_in[6], atl2, in_sizes[6],
                                             d_in[7], atr2, in_sizes[7],
                                             d_in[9], bfp1, in_sizes[9],
                                             d_in[11], bfp2, in_sizes[11], flags);
    convh_kernel<<<(in_sizes[0] + 255) / 256, 256, 0, stream>>>(d_in[0], x16, in_sizes[0], flags);
    {
        int nt = in_sizes[2] + in_sizes[5] + in_sizes[8] + in_sizes[10];
        conv4_kernel<<<(nt + 255) / 256, 256, 0, stream>>>(
            d_in[2], W1f, in_sizes[2],
            d_in[5], W2f, in_sizes[5],
            d_in[8], Wp1f, in_sizes[8],
            d_in[10], Wp2f, in_sizes[10], flags);
    }

    // 1. CSR build
    hipMemsetAsync(counts, 0, (size_t)N * 4, stream);
    count_kernel<<<EB, 256, 0, stream>>>(ei, E, flags, counts);
    scan1_kernel<<<NB1024, 1024, 0, stream>>>(counts, incl, bsum, N);
    scan2_kernel<<<1, 64, 0, stream>>>(bsum, boffs, NB1024, row_ptr, N);
    scan3_kernel<<<(N + 255) / 256, 256, 0, stream>>>(incl, counts, boffs, row_ptr, fill, N);
    scatter_kernel<<<EB, 256, 0, stream>>>(ei, E, flags, fill, esrc);

    // 2. GAT layer 1: xl16 = x@W1^T (alpha fused), K=128
    gemm_bt<128, 16, false, true, 2><<<GM, 256, 0, stream>>>(
        x16, W1f, nullptr, nullptr, xl16, atl1, atr1, al, ar, N);
    agg_fused_kernel<<<AGG_B, 256, 0, stream>>>(xl16, al, ar, row_ptr, esrc, h16, N);

    // 3. GAT layer 2: xl16 = h1@W2^T (alpha fused), K=256
    gemm_bt<256, 16, false, true, 2><<<GM, 256, 0, stream>>>(
        h16, W2f, nullptr, nullptr, xl16, atl2, atr2, al, ar, N);
    agg_fused_kernel<<<AGG_B, 256, 0, stream>>>(xl16, al, ar, row_ptr, esrc, h16, N);

    // 4. projections: p = h2@Wp1^T + bp1 (K=256, O=128, fp16 out into x16)
    gemm_bt<256, 8, true, false, 2><<<GM, 256, 0, stream>>>(
        h16, Wp1f, bfp1, nullptr, x16, nullptr, nullptr, nullptr, nullptr, N);
    // out = p@Wp2^T + bp2 (K=128, O=128) -> f32 d_out
    gemm_bt<128, 8, true, false, 0><<<GM, 256, 0, stream>>>(
        x16, Wp2f, bfp2, (float*)d_out, nullptr, nullptr, nullptr, nullptr, nullptr, N);
}